// Round 1
// baseline (2403.246 us; speedup 1.0000x reference)
//
#include <hip/hip_runtime.h>
#include <hip/hip_bf16.h>
#include <math.h>

// Problem constants
#define Bz 8
#define Lz 2048
#define Dz 512
#define KTOP 15

// ---------------------------------------------------------------------------
// GEMM: out[m,n] = sum_k A[m,k]*W[k,n] + bias[n]
// M=16384, N=512, K=512. 64x64 tile, 256 threads, 4x4 microtile, BK=16.
// ---------------------------------------------------------------------------
__global__ __launch_bounds__(256) void gemm_bias(
    const float* __restrict__ A, const float* __restrict__ W,
    const float* __restrict__ bias, float* __restrict__ out,
    int M, int N, int K) {
  __shared__ float As[16][68];  // [kk][m], padded row stride 68 (16B-aligned rows)
  __shared__ float Bs[16][68];  // [kk][n]
  const int tid = threadIdx.x;
  const int m0 = blockIdx.y * 64;
  const int n0 = blockIdx.x * 64;
  const int tx = tid & 15, ty = tid >> 4;

  float c[4][4] = {};

  for (int k0 = 0; k0 < K; k0 += 16) {
    // Load A tile: 64 rows x 16 k. Thread: m = tid>>2, 4 consecutive k.
    {
      const int m = tid >> 2;
      const int kq = (tid & 3) * 4;
      const float4 a4 = *(const float4*)&A[(size_t)(m0 + m) * K + k0 + kq];
      As[kq + 0][m] = a4.x;
      As[kq + 1][m] = a4.y;
      As[kq + 2][m] = a4.z;
      As[kq + 3][m] = a4.w;
      // Load B tile: 16 k-rows x 64 n.
      const int kk = tid >> 4;
      const int nq = (tid & 15) * 4;
      const float4 b4 = *(const float4*)&W[(size_t)(k0 + kk) * N + n0 + nq];
      *(float4*)&Bs[kk][nq] = b4;
    }
    __syncthreads();
    #pragma unroll
    for (int kk = 0; kk < 16; ++kk) {
      float4 a4 = *(const float4*)&As[kk][ty * 4];
      float4 b4 = *(const float4*)&Bs[kk][tx * 4];
      float a[4] = {a4.x, a4.y, a4.z, a4.w};
      float b[4] = {b4.x, b4.y, b4.z, b4.w};
      #pragma unroll
      for (int i = 0; i < 4; ++i)
        #pragma unroll
        for (int j = 0; j < 4; ++j)
          c[i][j] += a[i] * b[j];
    }
    __syncthreads();
  }

  const float4 bb = *(const float4*)&bias[n0 + tx * 4];
  const float bv[4] = {bb.x, bb.y, bb.z, bb.w};
  #pragma unroll
  for (int i = 0; i < 4; ++i) {
    float4 o;
    o.x = c[i][0] + bv[0];
    o.y = c[i][1] + bv[1];
    o.z = c[i][2] + bv[2];
    o.w = c[i][3] + bv[3];
    *(float4*)&out[(size_t)(m0 + ty * 4 + i) * N + n0 + tx * 4] = o;
  }
}

// ---------------------------------------------------------------------------
// Transpose per-batch (L x D) -> (D x L):  x[(b*L+l)*D + d] -> xT[(b*D+d)*L + l]
// ---------------------------------------------------------------------------
__global__ __launch_bounds__(256) void transpose_bld(
    const float* __restrict__ x, float* __restrict__ xT) {
  __shared__ float tile[32][33];
  const int d0 = blockIdx.x * 32;
  const int l0 = blockIdx.y * 32;
  const int b = blockIdx.z;
  const int tx = threadIdx.x, ty = threadIdx.y;
  const float* xb = x + (size_t)b * Lz * Dz;
  float* xTb = xT + (size_t)b * Dz * Lz;
  #pragma unroll
  for (int i = 0; i < 4; ++i)
    tile[ty + 8 * i][tx] = xb[(size_t)(l0 + ty + 8 * i) * Dz + d0 + tx];
  __syncthreads();
  #pragma unroll
  for (int i = 0; i < 4; ++i)
    xTb[(size_t)(d0 + ty + 8 * i) * Lz + l0 + tx] = tile[tx][ty + 8 * i];
}

// ---------------------------------------------------------------------------
// Per-channel circular correlation + top-15 + softmax.
// One block (256 threads) per (b,d) channel.
// r[tau] = sum_t q[t] * k[(t - tau) mod L]
// ---------------------------------------------------------------------------
__global__ __launch_bounds__(256) void corr_topk(
    const float* __restrict__ qT, const float* __restrict__ kT,
    float* __restrict__ Wk, int* __restrict__ Ik) {
  __shared__ float qs[Lz];
  __shared__ float ks[2 * Lz];
  __shared__ float rbuf[Lz];
  __shared__ float redv[256];
  __shared__ int redi[256];
  __shared__ float topv[16];
  __shared__ int topi[16];

  const int tid = threadIdx.x;
  const size_t chan = (size_t)blockIdx.x * Lz;

  for (int i = tid; i < Lz; i += 256) {
    float qv = qT[chan + i];
    float kv = kT[chan + i];
    qs[i] = qv;
    ks[i] = kv;
    ks[i + Lz] = kv;
  }
  __syncthreads();

  const int tau0 = tid * 8;
  const int kb = Lz - tau0;  // ks[kb + t - j] == k[(t - (tau0+j)) mod L]
  float acc[8] = {0.f, 0.f, 0.f, 0.f, 0.f, 0.f, 0.f, 0.f};
  float h[8];
  // init so that after the first shift, h[j] = ks[kb + t - j]
  #pragma unroll
  for (int j = 0; j < 7; ++j) h[j] = ks[kb - 1 - j];
  h[7] = 0.f;

  #pragma unroll 8
  for (int t = 0; t < Lz; ++t) {
    #pragma unroll
    for (int j = 7; j >= 1; --j) h[j] = h[j - 1];
    h[0] = ks[kb + t];
    const float qv = qs[t];
    #pragma unroll
    for (int j = 0; j < 8; ++j) acc[j] += qv * h[j];
  }

  #pragma unroll
  for (int j = 0; j < 8; ++j) rbuf[tau0 + j] = acc[j];
  __syncthreads();

  // Top-15 by repeated block-wide argmax; tie-break = lowest index (lax.top_k).
  for (int it = 0; it < KTOP; ++it) {
    float best = -3.0e38f;
    int bi = 0;
    #pragma unroll
    for (int j = 0; j < 8; ++j) {
      const float v = rbuf[tau0 + j];
      if (v > best) { best = v; bi = tau0 + j; }
    }
    redv[tid] = best;
    redi[tid] = bi;
    __syncthreads();
    for (int s = 128; s > 0; s >>= 1) {
      if (tid < s) {
        const float vo = redv[tid + s];
        const int io = redi[tid + s];
        if (vo > redv[tid] || (vo == redv[tid] && io < redi[tid])) {
          redv[tid] = vo;
          redi[tid] = io;
        }
      }
      __syncthreads();
    }
    if (tid == 0) {
      topv[it] = redv[0];
      topi[it] = redi[0];
      rbuf[redi[0]] = -3.0e38f;
    }
    __syncthreads();
  }

  if (tid == 0) {
    const float m = topv[0];  // sorted descending -> first is max
    float e[KTOP];
    float s = 0.f;
    #pragma unroll
    for (int k2 = 0; k2 < KTOP; ++k2) {
      e[k2] = expf(topv[k2] - m);
      s += e[k2];
    }
    const float inv = 1.0f / s;
    const size_t ob = (size_t)blockIdx.x * KTOP;
    #pragma unroll
    for (int k2 = 0; k2 < KTOP; ++k2) {
      Wk[ob + k2] = e[k2] * inv;
      Ik[ob + k2] = topi[k2];
    }
  }
}

// ---------------------------------------------------------------------------
// Output gather: A[b,l,d] = sum_k w[b,d,k] * v[b, (l+I[b,d,k]) mod L, d]
// Block: one b, 16 l values; thread = d (coalesced).
// ---------------------------------------------------------------------------
__global__ __launch_bounds__(512) void gather_out(
    const float* __restrict__ v, const float* __restrict__ Wk,
    const int* __restrict__ Ik, float* __restrict__ out) {
  const int d = threadIdx.x;
  const int b = blockIdx.y;
  const int l0 = blockIdx.x * 16;
  const size_t ch = ((size_t)b * Dz + d) * KTOP;
  float w[KTOP];
  int id[KTOP];
  #pragma unroll
  for (int k = 0; k < KTOP; ++k) {
    w[k] = Wk[ch + k];
    id[k] = Ik[ch + k];
  }
  const float* vb = v + (size_t)b * Lz * Dz;
  float* ob = out + (size_t)b * Lz * Dz;
  for (int li = 0; li < 16; ++li) {
    const int l = l0 + li;
    float acc = 0.f;
    #pragma unroll
    for (int k = 0; k < KTOP; ++k) {
      acc += w[k] * vb[(size_t)((l + id[k]) & (Lz - 1)) * Dz + d];
    }
    ob[(size_t)l * Dz + d] = acc;
  }
}

// ---------------------------------------------------------------------------
extern "C" void kernel_launch(void* const* d_in, const int* in_sizes, int n_in,
                              void* d_out, int out_size, void* d_ws, size_t ws_size,
                              hipStream_t stream) {
  const float* Q = (const float*)d_in[0];
  const float* K = (const float*)d_in[1];
  const float* V = (const float*)d_in[2];
  const float* WQw = (const float*)d_in[3];
  const float* WQb = (const float*)d_in[4];
  const float* WKw = (const float*)d_in[5];
  const float* WKb = (const float*)d_in[6];
  const float* WVw = (const float*)d_in[7];
  const float* WVb = (const float*)d_in[8];
  float* out = (float*)d_out;

  const size_t CH = (size_t)Bz * Dz;          // 4096 channels
  const size_t NEL = (size_t)Bz * Lz * Dz;    // 8388608 elements
  float* qT = (float*)d_ws;
  float* kT = qT + NEL;
  float* vbuf = kT + NEL;
  float* tmp = vbuf + NEL;
  float* Wk = tmp + NEL;
  int* Ik = (int*)(Wk + CH * KTOP);

  const int M = Bz * Lz;  // 16384
  dim3 gemm_grid(Dz / 64, M / 64);  // (8, 256)
  dim3 gemm_block(256);
  dim3 tr_grid(Dz / 32, Lz / 32, Bz);  // (16, 64, 8)
  dim3 tr_block(32, 8);

  // q = Q@WQ + b  -> tmp -> transpose -> qT
  gemm_bias<<<gemm_grid, gemm_block, 0, stream>>>(Q, WQw, WQb, tmp, M, Dz, Dz);
  transpose_bld<<<tr_grid, tr_block, 0, stream>>>(tmp, qT);
  // k = K@WK + b  -> tmp -> transpose -> kT
  gemm_bias<<<gemm_grid, gemm_block, 0, stream>>>(K, WKw, WKb, tmp, M, Dz, Dz);
  transpose_bld<<<tr_grid, tr_block, 0, stream>>>(tmp, kT);
  // v = V@WV + b  -> vbuf (stays (B,L,D))
  gemm_bias<<<gemm_grid, gemm_block, 0, stream>>>(V, WVw, WVb, vbuf, M, Dz, Dz);

  // correlation + top-k + softmax per (b,d) channel
  corr_topk<<<dim3((unsigned)CH), dim3(256), 0, stream>>>(qT, kT, Wk, Ik);

  // output gather
  gather_out<<<dim3(Lz / 16, Bz), dim3(512), 0, stream>>>(vbuf, Wk, Ik, out);
}

// Round 3
// 660.094 us; speedup vs baseline: 3.6408x; 3.6408x over previous
//
#include <hip/hip_runtime.h>
#include <hip/hip_bf16.h>
#include <math.h>

// Problem constants
#define Bz 8
#define Lz 2048
#define Dz 512
#define KTOP 15

typedef __attribute__((ext_vector_type(8))) unsigned short ushort8x;
typedef __attribute__((ext_vector_type(8))) _Float16 half8x;   // fp16x8 MFMA frag
typedef __attribute__((ext_vector_type(4))) float floatx4;     // fp32x4 MFMA acc

// ---------------------------------------------------------------------------
// GEMM: out[m,n] = sum_k A[m,k]*W[k,n] + bias[n]   (fp32, 64x64 tile)
// ---------------------------------------------------------------------------
__global__ __launch_bounds__(256) void gemm_bias(
    const float* __restrict__ A, const float* __restrict__ W,
    const float* __restrict__ bias, float* __restrict__ out,
    int M, int N, int K) {
  __shared__ float As[16][68];
  __shared__ float Bs[16][68];
  const int tid = threadIdx.x;
  const int m0 = blockIdx.y * 64;
  const int n0 = blockIdx.x * 64;
  const int tx = tid & 15, ty = tid >> 4;

  float c[4][4] = {};

  for (int k0 = 0; k0 < K; k0 += 16) {
    {
      const int m = tid >> 2;
      const int kq = (tid & 3) * 4;
      const float4 a4 = *(const float4*)&A[(size_t)(m0 + m) * K + k0 + kq];
      As[kq + 0][m] = a4.x;
      As[kq + 1][m] = a4.y;
      As[kq + 2][m] = a4.z;
      As[kq + 3][m] = a4.w;
      const int kk = tid >> 4;
      const int nq = (tid & 15) * 4;
      const float4 b4 = *(const float4*)&W[(size_t)(k0 + kk) * N + n0 + nq];
      *(float4*)&Bs[kk][nq] = b4;
    }
    __syncthreads();
    #pragma unroll
    for (int kk = 0; kk < 16; ++kk) {
      float4 a4 = *(const float4*)&As[kk][ty * 4];
      float4 b4 = *(const float4*)&Bs[kk][tx * 4];
      float a[4] = {a4.x, a4.y, a4.z, a4.w};
      float b[4] = {b4.x, b4.y, b4.z, b4.w};
      #pragma unroll
      for (int i = 0; i < 4; ++i)
        #pragma unroll
        for (int j = 0; j < 4; ++j)
          c[i][j] += a[i] * b[j];
    }
    __syncthreads();
  }

  const float4 bb = *(const float4*)&bias[n0 + tx * 4];
  const float bv[4] = {bb.x, bb.y, bb.z, bb.w};
  #pragma unroll
  for (int i = 0; i < 4; ++i) {
    float4 o;
    o.x = c[i][0] + bv[0];
    o.y = c[i][1] + bv[1];
    o.z = c[i][2] + bv[2];
    o.w = c[i][3] + bv[3];
    *(float4*)&out[(size_t)(m0 + ty * 4 + i) * N + n0 + tx * 4] = o;
  }
}

// ---------------------------------------------------------------------------
// Generic per-batch transpose (R x C) -> (C x R), fp32 -> fp32
// ---------------------------------------------------------------------------
__global__ __launch_bounds__(256) void transpose_f32(
    const float* __restrict__ in, float* __restrict__ out, int R, int C) {
  __shared__ float tile[32][33];
  const int c0 = blockIdx.x * 32;
  const int r0 = blockIdx.y * 32;
  const int b = blockIdx.z;
  const int tx = threadIdx.x, ty = threadIdx.y;
  const float* ib = in + (size_t)b * R * C;
  float* ob = out + (size_t)b * R * C;
  #pragma unroll
  for (int i = 0; i < 4; ++i)
    tile[ty + 8 * i][tx] = ib[(size_t)(r0 + ty + 8 * i) * C + c0 + tx];
  __syncthreads();
  #pragma unroll
  for (int i = 0; i < 4; ++i)
    ob[(size_t)(c0 + ty + 8 * i) * R + r0 + tx] = tile[tx][ty + 8 * i];
}

// Same but converts to fp16 on store.
__global__ __launch_bounds__(256) void transpose_f32_fp16(
    const float* __restrict__ in, _Float16* __restrict__ out, int R, int C) {
  __shared__ float tile[32][33];
  const int c0 = blockIdx.x * 32;
  const int r0 = blockIdx.y * 32;
  const int b = blockIdx.z;
  const int tx = threadIdx.x, ty = threadIdx.y;
  const float* ib = in + (size_t)b * R * C;
  _Float16* ob = out + (size_t)b * R * C;
  #pragma unroll
  for (int i = 0; i < 4; ++i)
    tile[ty + 8 * i][tx] = ib[(size_t)(r0 + ty + 8 * i) * C + c0 + tx];
  __syncthreads();
  #pragma unroll
  for (int i = 0; i < 4; ++i)
    ob[(size_t)(c0 + ty + 8 * i) * R + r0 + tx] =
        (_Float16)tile[tx][ty + 8 * i];
}

// ---------------------------------------------------------------------------
// Per-channel circular correlation via fp16 MFMA + top-15 + softmax.
// One block (256 threads, 4 waves) per (b,d) channel.
//
// r[tau] = sum_t q[t] * k[(t - tau) mod L],  tau = 256p + m + 16n
// D[m,n](p) = sum_{t0,kk} A[m,kk]*B_p[kk,n]
//   A[m,kk]   = q[(t0 + m + kk) mod L]         (indep of p,n)
//   B_p[kk,n] = k[(t0 + kk - 256p - 16n) mod L]
// 16x16x32 layouts: A[m=lane&15][kk=8*quad+j]; B[kk=8*quad+j][n=lane&15];
// D: col=lane&15, row=4*quad+reg.
// ---------------------------------------------------------------------------
#define QXS 2120  // per-shift-copy stride (elements), mult of 8, bank-spread
__global__ __launch_bounds__(256) void corr_mfma_topk(
    const _Float16* __restrict__ qT, const _Float16* __restrict__ kT,
    float* __restrict__ Wk, int* __restrict__ Ik) {
  __shared__ unsigned short qx[8 * QXS];  // 8 shifted copies of q (~33 KB)
  __shared__ unsigned short ke[4096];     // circularly doubled k (8 KB)
  __shared__ float rbuf[Lz];              // correlation result (8 KB)
  __shared__ float redv[256];
  __shared__ int redi[256];
  __shared__ float topv[16];
  __shared__ int topi[16];

  const int tid = threadIdx.x;
  const size_t chan = (size_t)blockIdx.x * Lz;
  const unsigned short* qg = (const unsigned short*)(qT + chan);
  const unsigned short* kg = (const unsigned short*)(kT + chan);

  // Stage ke[i] = k[i mod L], i in [0, 2L)
  for (int c = tid; c < 512; c += 256) {
    ushort8x v = *(const ushort8x*)(kg + ((8 * c) & (Lz - 1)));
    *(ushort8x*)(ke + 8 * c) = v;
  }
  // Stage qx[s][i] = q[(i+s) mod L], i in [0, QXS) for s in [0,8)
  for (int c = tid; c < QXS / 8; c += 256) {
    union { unsigned short u[16]; ushort8x v[2]; } b;
    b.v[0] = *(const ushort8x*)(qg + ((8 * c) & (Lz - 1)));
    b.v[1] = *(const ushort8x*)(qg + ((8 * c + 8) & (Lz - 1)));
    #pragma unroll
    for (int s = 0; s < 8; ++s) {
      ushort8x w;
      #pragma unroll
      for (int t = 0; t < 8; ++t) w[t] = b.u[s + t];
      *(ushort8x*)(qx + s * QXS + 8 * c) = w;
    }
  }
  __syncthreads();

  // --- MFMA main loop: wave wv handles p = wv and p = wv+4 ---
  const int lane = tid & 63;
  const int wv = tid >> 6;
  const int m = lane & 15;       // A row / B col (n)
  const int quad = lane >> 4;    // k-chunk selector
  const int s = m & 7;
  const unsigned short* qxs = qx + s * QXS + (m & 8) + 8 * quad;
  const int bb0 = Lz + 8 * quad - 16 * m - 256 * wv;
  const int bb1 = bb0 - 256 * 4;

  floatx4 acc0 = {0.f, 0.f, 0.f, 0.f};
  floatx4 acc1 = {0.f, 0.f, 0.f, 0.f};
  #pragma unroll 4
  for (int t0 = 0; t0 < Lz; t0 += 32) {
    half8x a = *(const half8x*)(qxs + t0);
    half8x b0 = *(const half8x*)(ke + bb0 + t0);
    half8x b1 = *(const half8x*)(ke + bb1 + t0);
    acc0 = __builtin_amdgcn_mfma_f32_16x16x32_f16(a, b0, acc0, 0, 0, 0);
    acc1 = __builtin_amdgcn_mfma_f32_16x16x32_f16(a, b1, acc1, 0, 0, 0);
  }
  // Write r: tau = 256p + row + 16*col, row = 4*quad + reg, col = m
  #pragma unroll
  for (int r = 0; r < 4; ++r) {
    rbuf[256 * wv + 4 * quad + r + 16 * m] = acc0[r];
    rbuf[256 * (wv + 4) + 4 * quad + r + 16 * m] = acc1[r];
  }
  __syncthreads();

  // --- Top-15 by repeated block argmax; tie-break lowest index ---
  const int tau0 = tid * 8;
  for (int it = 0; it < KTOP; ++it) {
    float best = -3.0e38f;
    int bi = 0;
    #pragma unroll
    for (int j = 0; j < 8; ++j) {
      const float v = rbuf[tau0 + j];
      if (v > best) { best = v; bi = tau0 + j; }
    }
    redv[tid] = best;
    redi[tid] = bi;
    __syncthreads();
    for (int st = 128; st > 0; st >>= 1) {
      if (tid < st) {
        const float vo = redv[tid + st];
        const int io = redi[tid + st];
        if (vo > redv[tid] || (vo == redv[tid] && io < redi[tid])) {
          redv[tid] = vo;
          redi[tid] = io;
        }
      }
      __syncthreads();
    }
    if (tid == 0) {
      topv[it] = redv[0];
      topi[it] = redi[0];
      rbuf[redi[0]] = -3.0e38f;
    }
    __syncthreads();
  }

  if (tid == 0) {
    const float mx = topv[0];
    float e[KTOP];
    float sum = 0.f;
    #pragma unroll
    for (int k2 = 0; k2 < KTOP; ++k2) {
      e[k2] = expf(topv[k2] - mx);
      sum += e[k2];
    }
    const float inv = 1.0f / sum;
    const size_t ob = (size_t)blockIdx.x * KTOP;
    #pragma unroll
    for (int k2 = 0; k2 < KTOP; ++k2) {
      Wk[ob + k2] = e[k2] * inv;
      Ik[ob + k2] = topi[k2];
    }
  }
}

// ---------------------------------------------------------------------------
// Channel-major gather: outT[b,d,l] = sum_k w[b,d,k] * vT[b,d,(l+I[b,d,k]) mod L]
// One block (256 threads) per (b,d) channel; v channel staged in LDS.
// ---------------------------------------------------------------------------
__global__ __launch_bounds__(256) void gather_chan(
    const float* __restrict__ vT, const float* __restrict__ Wk,
    const int* __restrict__ Ik, float* __restrict__ outT) {
  __shared__ float ls[2 * Lz];
  const int tid = threadIdx.x;
  const size_t chan = (size_t)blockIdx.x * Lz;
  const float* vch = vT + chan;
  for (int c = tid; c < Lz / 4; c += 256) {
    float4 v4 = *(const float4*)(vch + 4 * c);
    *(float4*)(ls + 4 * c) = v4;
    *(float4*)(ls + 4 * c + Lz) = v4;
  }
  __syncthreads();

  const size_t wb = (size_t)blockIdx.x * KTOP;
  float acc[8] = {0.f, 0.f, 0.f, 0.f, 0.f, 0.f, 0.f, 0.f};
  for (int k = 0; k < KTOP; ++k) {
    const float w = Wk[wb + k];
    const int id = Ik[wb + k];
    const float* p = ls + tid + id;
    #pragma unroll
    for (int j = 0; j < 8; ++j) acc[j] += w * p[256 * j];
  }
  float* och = outT + chan;
  #pragma unroll
  for (int j = 0; j < 8; ++j) och[tid + 256 * j] = acc[j];
}

// ---------------------------------------------------------------------------
extern "C" void kernel_launch(void* const* d_in, const int* in_sizes, int n_in,
                              void* d_out, int out_size, void* d_ws, size_t ws_size,
                              hipStream_t stream) {
  const float* Q = (const float*)d_in[0];
  const float* K = (const float*)d_in[1];
  const float* V = (const float*)d_in[2];
  const float* WQw = (const float*)d_in[3];
  const float* WQb = (const float*)d_in[4];
  const float* WKw = (const float*)d_in[5];
  const float* WKb = (const float*)d_in[6];
  const float* WVw = (const float*)d_in[7];
  const float* WVb = (const float*)d_in[8];
  float* out = (float*)d_out;

  const size_t CH = (size_t)Bz * Dz;        // 4096 channels
  const size_t NEL = (size_t)Bz * Lz * Dz;  // 8388608 elements

  char* ws = (char*)d_ws;
  float* tmp = (float*)ws;                       // NEL fp32
  float* vT = (float*)(ws + NEL * 4);            // NEL fp32
  _Float16* qT = (_Float16*)(ws + 2 * NEL * 4);            // NEL fp16
  _Float16* kT = (_Float16*)(ws + 2 * NEL * 4 + NEL * 2);  // NEL fp16
  float* Wk = (float*)(ws + 2 * NEL * 4 + 2 * NEL * 2);
  int* Ik = (int*)(Wk + CH * KTOP);

  const int M = Bz * Lz;  // 16384
  dim3 gemm_grid(Dz / 64, M / 64);
  dim3 gemm_block(256);
  dim3 trLD_grid(Dz / 32, Lz / 32, Bz);  // (L x D) -> (D x L)
  dim3 trDL_grid(Lz / 32, Dz / 32, Bz);  // (D x L) -> (L x D)
  dim3 tr_block(32, 8);

  // q = Q@WQ + b -> tmp -> transpose+fp16 -> qT (B,D,L)
  gemm_bias<<<gemm_grid, gemm_block, 0, stream>>>(Q, WQw, WQb, tmp, M, Dz, Dz);
  transpose_f32_fp16<<<trLD_grid, tr_block, 0, stream>>>(tmp, qT, Lz, Dz);
  // k -> kT
  gemm_bias<<<gemm_grid, gemm_block, 0, stream>>>(K, WKw, WKb, tmp, M, Dz, Dz);
  transpose_f32_fp16<<<trLD_grid, tr_block, 0, stream>>>(tmp, kT, Lz, Dz);
  // v -> vT (fp32)
  gemm_bias<<<gemm_grid, gemm_block, 0, stream>>>(V, WVw, WVb, tmp, M, Dz, Dz);
  transpose_f32<<<trLD_grid, tr_block, 0, stream>>>(tmp, vT, Lz, Dz);

  // correlation (MFMA) + top-k + softmax per channel
  corr_mfma_topk<<<dim3((unsigned)CH), dim3(256), 0, stream>>>(qT, kT, Wk, Ik);

  // channel-major gather -> tmp as outT (B,D,L)
  gather_chan<<<dim3((unsigned)CH), dim3(256), 0, stream>>>(vT, Wk, Ik, tmp);

  // outT (B,D,L) -> out (B,L,D)
  transpose_f32<<<trDL_grid, tr_block, 0, stream>>>(tmp, out, Dz, Lz);
}

// Round 4
// 386.624 us; speedup vs baseline: 6.2160x; 1.7073x over previous
//
#include <hip/hip_runtime.h>
#include <hip/hip_bf16.h>
#include <math.h>

// Problem constants
#define Bz 8
#define Lz 2048
#define Dz 512
#define KTOP 15

typedef __attribute__((ext_vector_type(8))) unsigned short ushort8x;
typedef __attribute__((ext_vector_type(8))) _Float16 half8x;   // fp16x8 MFMA frag
typedef __attribute__((ext_vector_type(4))) float floatx4;     // fp32x4 MFMA acc

// ---------------------------------------------------------------------------
// Cast fp32 -> fp16 elementwise (grid-stride over float4 groups)
// ---------------------------------------------------------------------------
__global__ __launch_bounds__(256) void cast_f32_f16(
    const float* __restrict__ s, _Float16* __restrict__ d, int n4) {
  int i = blockIdx.x * 256 + threadIdx.x;
  const int stride = gridDim.x * 256;
  for (; i < n4; i += stride) {
    float4 v = *(const float4*)(s + 4 * (size_t)i);
    union { _Float16 h[4]; unsigned long long u; } p;
    p.h[0] = (_Float16)v.x;
    p.h[1] = (_Float16)v.y;
    p.h[2] = (_Float16)v.z;
    p.h[3] = (_Float16)v.w;
    *(unsigned long long*)(d + 4 * (size_t)i) = p.u;
  }
}

// ---------------------------------------------------------------------------
// Transpose-cast the 3 weight matrices (K x N fp32) -> (N x K fp16)
// grid (16,16,3), block (32,8)
// ---------------------------------------------------------------------------
__global__ __launch_bounds__(256) void wtrans3(
    const float* __restrict__ w0, const float* __restrict__ w1,
    const float* __restrict__ w2, _Float16* __restrict__ t0,
    _Float16* __restrict__ t1, _Float16* __restrict__ t2) {
  const float* w = blockIdx.z == 0 ? w0 : (blockIdx.z == 1 ? w1 : w2);
  _Float16* t = blockIdx.z == 0 ? t0 : (blockIdx.z == 1 ? t1 : t2);
  __shared__ float tile[32][33];
  const int n0 = blockIdx.x * 32, k0 = blockIdx.y * 32;
  const int tx = threadIdx.x, ty = threadIdx.y;
  #pragma unroll
  for (int i = 0; i < 4; ++i)
    tile[ty + 8 * i][tx] = w[(size_t)(k0 + ty + 8 * i) * Dz + n0 + tx];
  __syncthreads();
  #pragma unroll
  for (int i = 0; i < 4; ++i)
    t[(size_t)(n0 + ty + 8 * i) * Dz + k0 + tx] = (_Float16)tile[tx][ty + 8 * i];
}

// ---------------------------------------------------------------------------
// MFMA GEMM: out[m,n] = sum_k A[m,k]*Bt[n,k] + bias[n]
// A: M x K fp16 row-major; Bt: N x K fp16 (W transposed); out fp32.
// 128x128 tile, 256 threads (4 waves, 2x2), 4x4 frags of 16x16x32, BK=32.
// Double-buffered LDS + register prefetch.
// ---------------------------------------------------------------------------
#define GLDA 40  // padded LDS row stride (fp16 elements); 80 B = 20 banks -> 2-way
__global__ __launch_bounds__(256) void gemm_mfma(
    const _Float16* __restrict__ A, const _Float16* __restrict__ Bt,
    const float* __restrict__ bias, float* __restrict__ out,
    int M, int N, int K) {
  __shared__ _Float16 As[2][128 * GLDA];
  __shared__ _Float16 Bs[2][128 * GLDA];
  const int tid = threadIdx.x;
  const int m0 = blockIdx.y * 128;
  const int n0 = blockIdx.x * 128;
  const int lane = tid & 63;
  const int wv = tid >> 6;
  const int wr = wv & 1, wc = wv >> 1;
  const int ln = lane & 15;
  const int quad = lane >> 4;

  floatx4 acc[4][4];
  #pragma unroll
  for (int i = 0; i < 4; ++i)
    #pragma unroll
    for (int j = 0; j < 4; ++j) acc[i][j] = (floatx4){0.f, 0.f, 0.f, 0.f};

  ushort8x ra[2], rb[2];
  // prologue: load k-tile 0 -> regs -> LDS[0]
  #pragma unroll
  for (int j = 0; j < 2; ++j) {
    const int slot = tid + 256 * j;
    const int r = slot >> 2, ch = slot & 3;
    ra[j] = *(const ushort8x*)(A + (size_t)(m0 + r) * K + ch * 8);
    rb[j] = *(const ushort8x*)(Bt + (size_t)(n0 + r) * K + ch * 8);
  }
  #pragma unroll
  for (int j = 0; j < 2; ++j) {
    const int slot = tid + 256 * j;
    const int r = slot >> 2, ch = slot & 3;
    *(ushort8x*)(&As[0][r * GLDA + ch * 8]) = ra[j];
    *(ushort8x*)(&Bs[0][r * GLDA + ch * 8]) = rb[j];
  }
  __syncthreads();

  const int NKT = K / 32;
  for (int kt = 0; kt < NKT; ++kt) {
    const int cur = kt & 1;
    if (kt + 1 < NKT) {
      const int kof = (kt + 1) * 32;
      #pragma unroll
      for (int j = 0; j < 2; ++j) {
        const int slot = tid + 256 * j;
        const int r = slot >> 2, ch = slot & 3;
        ra[j] = *(const ushort8x*)(A + (size_t)(m0 + r) * K + kof + ch * 8);
        rb[j] = *(const ushort8x*)(Bt + (size_t)(n0 + r) * K + kof + ch * 8);
      }
    }
    half8x af[4], bf[4];
    #pragma unroll
    for (int i = 0; i < 4; ++i)
      af[i] = *(const half8x*)(&As[cur][(wr * 64 + 16 * i + ln) * GLDA + 8 * quad]);
    #pragma unroll
    for (int j = 0; j < 4; ++j)
      bf[j] = *(const half8x*)(&Bs[cur][(wc * 64 + 16 * j + ln) * GLDA + 8 * quad]);
    #pragma unroll
    for (int i = 0; i < 4; ++i)
      #pragma unroll
      for (int j = 0; j < 4; ++j)
        acc[i][j] = __builtin_amdgcn_mfma_f32_16x16x32_f16(af[i], bf[j], acc[i][j], 0, 0, 0);
    if (kt + 1 < NKT) {
      const int nxt = cur ^ 1;
      #pragma unroll
      for (int j = 0; j < 2; ++j) {
        const int slot = tid + 256 * j;
        const int r = slot >> 2, ch = slot & 3;
        *(ushort8x*)(&As[nxt][r * GLDA + ch * 8]) = ra[j];
        *(ushort8x*)(&Bs[nxt][r * GLDA + ch * 8]) = rb[j];
      }
      __syncthreads();
    }
  }

  // epilogue: C/D layout col=ln, row=4*quad+r
  #pragma unroll
  for (int j = 0; j < 4; ++j) {
    const int col = n0 + wc * 64 + 16 * j + ln;
    const float bv = bias[col];
    #pragma unroll
    for (int i = 0; i < 4; ++i) {
      const int rowb = m0 + wr * 64 + 16 * i + 4 * quad;
      #pragma unroll
      for (int r = 0; r < 4; ++r)
        out[(size_t)(rowb + r) * N + col] = acc[i][j][r] + bv;
    }
  }
}

// ---------------------------------------------------------------------------
// Generic per-batch transpose (R x C) -> (C x R), fp32 -> fp32
// ---------------------------------------------------------------------------
__global__ __launch_bounds__(256) void transpose_f32(
    const float* __restrict__ in, float* __restrict__ out, int R, int C) {
  __shared__ float tile[32][33];
  const int c0 = blockIdx.x * 32;
  const int r0 = blockIdx.y * 32;
  const int b = blockIdx.z;
  const int tx = threadIdx.x, ty = threadIdx.y;
  const float* ib = in + (size_t)b * R * C;
  float* ob = out + (size_t)b * R * C;
  #pragma unroll
  for (int i = 0; i < 4; ++i)
    tile[ty + 8 * i][tx] = ib[(size_t)(r0 + ty + 8 * i) * C + c0 + tx];
  __syncthreads();
  #pragma unroll
  for (int i = 0; i < 4; ++i)
    ob[(size_t)(c0 + ty + 8 * i) * R + r0 + tx] = tile[tx][ty + 8 * i];
}

// Same but converts to fp16 on store.
__global__ __launch_bounds__(256) void transpose_f32_fp16(
    const float* __restrict__ in, _Float16* __restrict__ out, int R, int C) {
  __shared__ float tile[32][33];
  const int c0 = blockIdx.x * 32;
  const int r0 = blockIdx.y * 32;
  const int b = blockIdx.z;
  const int tx = threadIdx.x, ty = threadIdx.y;
  const float* ib = in + (size_t)b * R * C;
  _Float16* ob = out + (size_t)b * R * C;
  #pragma unroll
  for (int i = 0; i < 4; ++i)
    tile[ty + 8 * i][tx] = ib[(size_t)(r0 + ty + 8 * i) * C + c0 + tx];
  __syncthreads();
  #pragma unroll
  for (int i = 0; i < 4; ++i)
    ob[(size_t)(c0 + ty + 8 * i) * R + r0 + tx] =
        (_Float16)tile[tx][ty + 8 * i];
}

// ---------------------------------------------------------------------------
// Per-channel circular correlation via fp16 MFMA + register top-15 + softmax.
// One block (256 threads, 4 waves) per (b,d) channel.
// r[tau] = sum_t q[t] * k[(t - tau) mod L],  tau = 256p + m + 16n
//   A[m,kk]   = q[(t0 + m + kk) mod L]
//   B_p[kk,n] = k[(t0 + kk - 256p - 16n) mod L]
// 16x16x32 layouts: A[m=lane&15][kk=8*quad+j]; B[kk=8*quad+j][n=lane&15];
// D: col=lane&15 (n), row=4*quad+reg (m).
// Thread (wv,quad,m) owns tau = 256*wv + 4*quad + reg + 16*m (acc0)
//                     and tau + 1024 (acc1) -> top-k entirely in registers.
// ---------------------------------------------------------------------------
#define QXS 2120  // per-shift-copy stride (elements)
__global__ __launch_bounds__(256) void corr_mfma_topk(
    const _Float16* __restrict__ qT, const _Float16* __restrict__ kT,
    float* __restrict__ Wk, int* __restrict__ Ik) {
  __shared__ unsigned short qx[8 * QXS];  // 8 shifted copies of q (~33 KB)
  __shared__ unsigned short ke[4096];     // circularly doubled k (8 KB)
  __shared__ float wvv[4];
  __shared__ int wvi[4];

  const int tid = threadIdx.x;
  const size_t chan = (size_t)blockIdx.x * Lz;
  const unsigned short* qg = (const unsigned short*)(qT + chan);
  const unsigned short* kg = (const unsigned short*)(kT + chan);

  for (int c = tid; c < 512; c += 256) {
    ushort8x v = *(const ushort8x*)(kg + ((8 * c) & (Lz - 1)));
    *(ushort8x*)(ke + 8 * c) = v;
  }
  for (int c = tid; c < QXS / 8; c += 256) {
    union { unsigned short u[16]; ushort8x v[2]; } b;
    b.v[0] = *(const ushort8x*)(qg + ((8 * c) & (Lz - 1)));
    b.v[1] = *(const ushort8x*)(qg + ((8 * c + 8) & (Lz - 1)));
    #pragma unroll
    for (int s = 0; s < 8; ++s) {
      ushort8x w;
      #pragma unroll
      for (int t = 0; t < 8; ++t) w[t] = b.u[s + t];
      *(ushort8x*)(qx + s * QXS + 8 * c) = w;
    }
  }
  __syncthreads();

  const int lane = tid & 63;
  const int wv = tid >> 6;
  const int m = lane & 15;
  const int quad = lane >> 4;
  const int s = m & 7;
  const unsigned short* qxs = qx + s * QXS + (m & 8) + 8 * quad;
  const int bb0 = Lz + 8 * quad - 16 * m - 256 * wv;
  const int bb1 = bb0 - 256 * 4;

  floatx4 acc0 = {0.f, 0.f, 0.f, 0.f};
  floatx4 acc1 = {0.f, 0.f, 0.f, 0.f};
  #pragma unroll 4
  for (int t0 = 0; t0 < Lz; t0 += 32) {
    half8x a = *(const half8x*)(qxs + t0);
    half8x b0 = *(const half8x*)(ke + bb0 + t0);
    half8x b1 = *(const half8x*)(ke + bb1 + t0);
    acc0 = __builtin_amdgcn_mfma_f32_16x16x32_f16(a, b0, acc0, 0, 0, 0);
    acc1 = __builtin_amdgcn_mfma_f32_16x16x32_f16(a, b1, acc1, 0, 0, 0);
  }

  // --- register top-15 ---
  const int tbase = 256 * wv + 4 * quad + 16 * m;
  float vals[8];
  #pragma unroll
  for (int r = 0; r < 4; ++r) {
    vals[r] = acc0[r];
    vals[4 + r] = acc1[r];
  }

  float gmax = 0.f, esum = 0.f, selv = 0.f;
  int seli = 0;
  for (int it = 0; it < KTOP; ++it) {
    // thread-local argmax (idx ascending in j -> strict > keeps lowest idx)
    float bv = vals[0];
    int bj = 0;
    #pragma unroll
    for (int j = 1; j < 8; ++j)
      if (vals[j] > bv) { bv = vals[j]; bj = j; }
    int bi = tbase + (bj & 3) + ((bj >> 2) << 10);
    // 64-lane butterfly argmax, tie-break lowest index
    #pragma unroll
    for (int off = 1; off < 64; off <<= 1) {
      const float ov = __shfl_xor(bv, off, 64);
      const int oi = __shfl_xor(bi, off, 64);
      if (ov > bv || (ov == bv && oi < bi)) { bv = ov; bi = oi; }
    }
    if (lane == 0) { wvv[wv] = bv; wvi[wv] = bi; }
    __syncthreads();
    float gv = wvv[0];
    int gi = wvi[0];
    #pragma unroll
    for (int w2 = 1; w2 < 4; ++w2) {
      const float ov = wvv[w2];
      const int oi = wvi[w2];
      if (ov > gv || (ov == gv && oi < gi)) { gv = ov; gi = oi; }
    }
    __syncthreads();  // protect wvv/wvi before next iteration's writes
    if (it == 0) gmax = gv;
    esum += expf(gv - gmax);
    if (tid == it) { selv = gv; seli = gi; }
    // remove winner from its owner's registers (unique match)
    const int rel = gi - tbase;
    #pragma unroll
    for (int j = 0; j < 8; ++j) {
      const int rj = (j & 3) + ((j >> 2) << 10);
      if (rel == rj) vals[j] = -3.0e38f;
    }
  }

  if (tid < KTOP) {
    const size_t ob = (size_t)blockIdx.x * KTOP;
    Wk[ob + tid] = expf(selv - gmax) / esum;
    Ik[ob + tid] = seli;
  }
}

// ---------------------------------------------------------------------------
// Channel-major gather: outT[b,d,l] = sum_k w[b,d,k] * vT[b,d,(l+I[b,d,k]) mod L]
// ---------------------------------------------------------------------------
__global__ __launch_bounds__(256) void gather_chan(
    const float* __restrict__ vT, const float* __restrict__ Wk,
    const int* __restrict__ Ik, float* __restrict__ outT) {
  __shared__ float ls[2 * Lz];
  const int tid = threadIdx.x;
  const size_t chan = (size_t)blockIdx.x * Lz;
  const float* vch = vT + chan;
  for (int c = tid; c < Lz / 4; c += 256) {
    float4 v4 = *(const float4*)(vch + 4 * c);
    *(float4*)(ls + 4 * c) = v4;
    *(float4*)(ls + 4 * c + Lz) = v4;
  }
  __syncthreads();

  const size_t wb = (size_t)blockIdx.x * KTOP;
  float acc[8] = {0.f, 0.f, 0.f, 0.f, 0.f, 0.f, 0.f, 0.f};
  for (int k = 0; k < KTOP; ++k) {
    const float w = Wk[wb + k];
    const int id = Ik[wb + k];
    const float* p = ls + tid + id;
    #pragma unroll
    for (int j = 0; j < 8; ++j) acc[j] += w * p[256 * j];
  }
  float* och = outT + chan;
  #pragma unroll
  for (int j = 0; j < 8; ++j) och[tid + 256 * j] = acc[j];
}

// ---------------------------------------------------------------------------
extern "C" void kernel_launch(void* const* d_in, const int* in_sizes, int n_in,
                              void* d_out, int out_size, void* d_ws, size_t ws_size,
                              hipStream_t stream) {
  const float* Q = (const float*)d_in[0];
  const float* K = (const float*)d_in[1];
  const float* V = (const float*)d_in[2];
  const float* WQw = (const float*)d_in[3];
  const float* WQb = (const float*)d_in[4];
  const float* WKw = (const float*)d_in[5];
  const float* WKb = (const float*)d_in[6];
  const float* WVw = (const float*)d_in[7];
  const float* WVb = (const float*)d_in[8];
  float* out = (float*)d_out;

  const size_t CH = (size_t)Bz * Dz;        // 4096 channels
  const size_t NEL = (size_t)Bz * Lz * Dz;  // 8388608 elements
  const int M = Bz * Lz;                    // 16384

  char* ws = (char*)d_ws;
  _Float16* Ah = (_Float16*)ws;                       // NEL fp16 (reused 3x)
  _Float16* WQt = (_Float16*)(ws + NEL * 2);          // 512*512 fp16
  _Float16* WKt = WQt + (size_t)Dz * Dz;
  _Float16* WVt = WKt + (size_t)Dz * Dz;
  char* p = (char*)(WVt + (size_t)Dz * Dz);
  float* tmp = (float*)p;                             // NEL fp32
  float* vT = (float*)(p + NEL * 4);                  // NEL fp32
  _Float16* qT = (_Float16*)(p + 2 * NEL * 4);        // NEL fp16
  _Float16* kT = (_Float16*)(p + 2 * NEL * 4 + NEL * 2);
  float* Wk = (float*)(p + 2 * NEL * 4 + 2 * NEL * 2);
  int* Ik = (int*)(Wk + CH * KTOP);

  dim3 gemm_grid(Dz / 128, M / 128);     // (4, 128)
  dim3 trLD_grid(Dz / 32, Lz / 32, Bz);  // (L x D) -> (D x L)
  dim3 trDL_grid(Lz / 32, Dz / 32, Bz);  // (D x L) -> (L x D)
  dim3 tr_block(32, 8);
  const int n4 = (int)(NEL / 4);

  // weights -> fp16 transposed (N x K), all three
  wtrans3<<<dim3(16, 16, 3), tr_block, 0, stream>>>(WQw, WKw, WVw, WQt, WKt, WVt);

  // q
  cast_f32_f16<<<dim3(2048), dim3(256), 0, stream>>>(Q, Ah, n4);
  gemm_mfma<<<gemm_grid, dim3(256), 0, stream>>>(Ah, WQt, WQb, tmp, M, Dz, Dz);
  transpose_f32_fp16<<<trLD_grid, tr_block, 0, stream>>>(tmp, qT, Lz, Dz);
  // k
  cast_f32_f16<<<dim3(2048), dim3(256), 0, stream>>>(K, Ah, n4);
  gemm_mfma<<<gemm_grid, dim3(256), 0, stream>>>(Ah, WKt, WKb, tmp, M, Dz, Dz);
  transpose_f32_fp16<<<trLD_grid, tr_block, 0, stream>>>(tmp, kT, Lz, Dz);
  // v
  cast_f32_f16<<<dim3(2048), dim3(256), 0, stream>>>(V, Ah, n4);
  gemm_mfma<<<gemm_grid, dim3(256), 0, stream>>>(Ah, WVt, WVb, tmp, M, Dz, Dz);
  transpose_f32<<<trLD_grid, tr_block, 0, stream>>>(tmp, vT, Lz, Dz);

  // correlation (MFMA) + register top-k + softmax per channel
  corr_mfma_topk<<<dim3((unsigned)CH), dim3(256), 0, stream>>>(qT, kT, Wk, Ik);

  // channel-major gather -> tmp as outT (B,D,L)
  gather_chan<<<dim3((unsigned)CH), dim3(256), 0, stream>>>(vT, Wk, Ik, tmp);

  // outT (B,D,L) -> out (B,L,D)
  transpose_f32<<<trDL_grid, tr_block, 0, stream>>>(tmp, out, Dz, Lz);
}

// Round 5
// 360.457 us; speedup vs baseline: 6.6672x; 1.0726x over previous
//
#include <hip/hip_runtime.h>
#include <hip/hip_bf16.h>
#include <math.h>

// Problem constants
#define Bz 8
#define Lz 2048
#define Dz 512
#define KTOP 15

typedef __attribute__((ext_vector_type(8))) unsigned short ushort8x;
typedef __attribute__((ext_vector_type(8))) _Float16 half8x;   // fp16x8 MFMA frag
typedef __attribute__((ext_vector_type(4))) float floatx4;     // fp32x4 MFMA acc

// ---------------------------------------------------------------------------
// Transpose-cast the 3 weight matrices (K x N fp32) -> (N x K fp16)
// grid (16,16,3), block (32,8)
// ---------------------------------------------------------------------------
__global__ __launch_bounds__(256) void wtrans3(
    const float* __restrict__ w0, const float* __restrict__ w1,
    const float* __restrict__ w2, _Float16* __restrict__ t0,
    _Float16* __restrict__ t1, _Float16* __restrict__ t2) {
  const float* w = blockIdx.z == 0 ? w0 : (blockIdx.z == 1 ? w1 : w2);
  _Float16* t = blockIdx.z == 0 ? t0 : (blockIdx.z == 1 ? t1 : t2);
  __shared__ float tile[32][33];
  const int n0 = blockIdx.x * 32, k0 = blockIdx.y * 32;
  const int tx = threadIdx.x, ty = threadIdx.y;
  #pragma unroll
  for (int i = 0; i < 4; ++i)
    tile[ty + 8 * i][tx] = w[(size_t)(k0 + ty + 8 * i) * Dz + n0 + tx];
  __syncthreads();
  #pragma unroll
  for (int i = 0; i < 4; ++i)
    t[(size_t)(n0 + ty + 8 * i) * Dz + k0 + tx] = (_Float16)tile[tx][ty + 8 * i];
}

// ---------------------------------------------------------------------------
// Fused MFMA GEMM: C[m,n] = sum_k A[m,k]*Bt[n,k] + bias[n]
// A: M x K fp32 (cast to fp16 during LDS staging); Bt: N x K fp16.
// modeT==1: write fp16 TRANSPOSED per batch -> outT[(b*N + n)*2048 + l]
// modeT==0: write fp32 natural -> out[m*N + n]
// 128x128 tile, 256 threads (4 waves 2x2), 4x4 frags of 16x16x32, BK=32,
// double-buffered LDS + register prefetch. M=16384, N=K=512.
// ---------------------------------------------------------------------------
#define GLDA 40  // padded LDS row stride (fp16 elems); 80B rows
__global__ __launch_bounds__(256) void gemm_fused(
    const float* __restrict__ A, const _Float16* __restrict__ Bt,
    const float* __restrict__ bias, void* __restrict__ outp, int modeT) {
  const int K = Dz, N = Dz;
  __shared__ _Float16 smem[20480];  // 40KB: As[2][5120] | Bs[2][5120]
  _Float16* Asb = smem;
  _Float16* Bsb = smem + 10240;
  const int tid = threadIdx.x;
  const int m0 = blockIdx.y * 128;
  const int n0 = blockIdx.x * 128;
  const int lane = tid & 63;
  const int wv = tid >> 6;
  const int wr = wv & 1, wc = wv >> 1;
  const int ln = lane & 15;
  const int quad = lane >> 4;

  floatx4 acc[4][4];
  #pragma unroll
  for (int i = 0; i < 4; ++i)
    #pragma unroll
    for (int j = 0; j < 4; ++j) acc[i][j] = (floatx4){0.f, 0.f, 0.f, 0.f};

  float4 ra4[4];
  ushort8x rb[2];

  // prologue: k-tile 0 -> regs -> LDS[0]
  #pragma unroll
  for (int j = 0; j < 4; ++j) {
    const int slot = tid + 256 * j;
    const int r = slot >> 3, c4 = slot & 7;
    ra4[j] = *(const float4*)&A[(size_t)(m0 + r) * K + 4 * c4];
  }
  #pragma unroll
  for (int j = 0; j < 2; ++j) {
    const int slot = tid + 256 * j;
    const int r = slot >> 2, ch = slot & 3;
    rb[j] = *(const ushort8x*)((const unsigned short*)Bt +
                               (size_t)(n0 + r) * K + 8 * ch);
  }
  {
    _Float16* As = Asb;
    _Float16* Bs = Bsb;
    #pragma unroll
    for (int j = 0; j < 4; ++j) {
      const int slot = tid + 256 * j;
      const int r = slot >> 3, c4 = slot & 7;
      union { _Float16 h[4]; unsigned long long u; } p;
      p.h[0] = (_Float16)ra4[j].x;
      p.h[1] = (_Float16)ra4[j].y;
      p.h[2] = (_Float16)ra4[j].z;
      p.h[3] = (_Float16)ra4[j].w;
      *(unsigned long long*)&As[r * GLDA + 4 * c4] = p.u;
    }
    #pragma unroll
    for (int j = 0; j < 2; ++j) {
      const int slot = tid + 256 * j;
      const int r = slot >> 2, ch = slot & 3;
      *(ushort8x*)&Bs[r * GLDA + 8 * ch] = rb[j];
    }
  }
  __syncthreads();

  const int NKT = K / 32;  // 16
  for (int kt = 0; kt < NKT; ++kt) {
    const int cur = kt & 1;
    if (kt + 1 < NKT) {
      const int kof = (kt + 1) * 32;
      #pragma unroll
      for (int j = 0; j < 4; ++j) {
        const int slot = tid + 256 * j;
        const int r = slot >> 3, c4 = slot & 7;
        ra4[j] = *(const float4*)&A[(size_t)(m0 + r) * K + kof + 4 * c4];
      }
      #pragma unroll
      for (int j = 0; j < 2; ++j) {
        const int slot = tid + 256 * j;
        const int r = slot >> 2, ch = slot & 3;
        rb[j] = *(const ushort8x*)((const unsigned short*)Bt +
                                   (size_t)(n0 + r) * K + kof + 8 * ch);
      }
    }
    const _Float16* As = Asb + cur * 5120;
    const _Float16* Bs = Bsb + cur * 5120;
    half8x af[4], bf[4];
    #pragma unroll
    for (int i = 0; i < 4; ++i)
      af[i] = *(const half8x*)&As[(wr * 64 + 16 * i + ln) * GLDA + 8 * quad];
    #pragma unroll
    for (int j = 0; j < 4; ++j)
      bf[j] = *(const half8x*)&Bs[(wc * 64 + 16 * j + ln) * GLDA + 8 * quad];
    #pragma unroll
    for (int i = 0; i < 4; ++i)
      #pragma unroll
      for (int j = 0; j < 4; ++j)
        acc[i][j] = __builtin_amdgcn_mfma_f32_16x16x32_f16(af[i], bf[j], acc[i][j], 0, 0, 0);
    if (kt + 1 < NKT) {
      const int nxt = cur ^ 1;
      _Float16* Asw = Asb + nxt * 5120;
      _Float16* Bsw = Bsb + nxt * 5120;
      #pragma unroll
      for (int j = 0; j < 4; ++j) {
        const int slot = tid + 256 * j;
        const int r = slot >> 3, c4 = slot & 7;
        union { _Float16 h[4]; unsigned long long u; } p;
        p.h[0] = (_Float16)ra4[j].x;
        p.h[1] = (_Float16)ra4[j].y;
        p.h[2] = (_Float16)ra4[j].z;
        p.h[3] = (_Float16)ra4[j].w;
        *(unsigned long long*)&Asw[r * GLDA + 4 * c4] = p.u;
      }
      #pragma unroll
      for (int j = 0; j < 2; ++j) {
        const int slot = tid + 256 * j;
        const int r = slot >> 2, ch = slot & 3;
        *(ushort8x*)&Bsw[r * GLDA + 8 * ch] = rb[j];
      }
      __syncthreads();
    }
  }

  if (modeT) {
    // epilogue: retranspose through LDS, write fp16 (B, N, L) layout
    __syncthreads();                 // all LDS frag reads done
    _Float16* TB = smem;             // [128][136] fp16 = 34816 B <= 40KB
    #pragma unroll
    for (int j = 0; j < 4; ++j) {
      const int n_l = wc * 64 + 16 * j + ln;
      const float bv = bias[n0 + n_l];
      #pragma unroll
      for (int i = 0; i < 4; ++i) {
        const int m_l = wr * 64 + 16 * i + 4 * quad;
        union { _Float16 h[4]; unsigned long long u; } p;
        #pragma unroll
        for (int r = 0; r < 4; ++r) p.h[r] = (_Float16)(acc[i][j][r] + bv);
        *(unsigned long long*)&TB[n_l * 136 + m_l] = p.u;
      }
    }
    __syncthreads();
    _Float16* oT = (_Float16*)outp;
    const int b = m0 >> 11;
    const int l0 = m0 & 2047;
    #pragma unroll
    for (int it = 0; it < 8; ++it) {
      const int s = tid + 256 * it;
      const int n = s >> 4, c = s & 15;
      *(ushort8x*)(oT + ((size_t)(b * Dz + n0 + n)) * Lz + l0 + 8 * c) =
          *(const ushort8x*)&TB[n * 136 + 8 * c];
    }
  } else {
    float* out = (float*)outp;
    #pragma unroll
    for (int j = 0; j < 4; ++j) {
      const int col = n0 + wc * 64 + 16 * j + ln;
      const float bv = bias[col];
      #pragma unroll
      for (int i = 0; i < 4; ++i) {
        const int rowb = m0 + wr * 64 + 16 * i + 4 * quad;
        #pragma unroll
        for (int r = 0; r < 4; ++r)
          out[(size_t)(rowb + r) * N + col] = acc[i][j][r] + bv;
      }
    }
  }
}

// ---------------------------------------------------------------------------
// Per-channel circular correlation via fp16 MFMA + barrier-free top-15.
// One block (256 threads, 4 waves) per (b,d) channel.
// r[tau] = sum_t q[t]*k[(t-tau) mod L], tau = 256p + m + 16n (p: wave wv,wv+4)
//   A[m,kk]=q[(t0+m+kk)%L]  (8 shifted LDS copies, stride 2056)
//   B_p[kk,n]=k[(t0+kk-256p-16n)%L]  (single copy + AND wrap)
// D: col=lane&15 (m here), row=4*quad+reg.
// Top-15: per-wave register extraction (butterfly), then wave-0 merges 60.
// ---------------------------------------------------------------------------
#define QXS2 2056  // 2048+8; stride/8 = 257 == 1 mod 8 -> bank spread
__global__ __launch_bounds__(256) void corr_mfma_topk(
    const _Float16* __restrict__ qT, const _Float16* __restrict__ kT,
    float* __restrict__ Wk, int* __restrict__ Ik) {
  __shared__ unsigned short qx[8 * QXS2];  // ~32.1 KB
  __shared__ unsigned short ke[Lz];        // 4 KB single copy
  __shared__ float cv[64];
  __shared__ int ci[64];

  const int tid = threadIdx.x;
  const size_t chan = (size_t)blockIdx.x * Lz;
  const unsigned short* qg = (const unsigned short*)(qT + chan);
  const unsigned short* kg = (const unsigned short*)(kT + chan);

  // ke[i] = k[i], i in [0, 2048)
  {
    ushort8x v = *(const ushort8x*)(kg + 8 * tid);
    *(ushort8x*)(ke + 8 * tid) = v;
  }
  // qx[s][i] = q[(i+s) mod L], i in [0, 2056)
  for (int c = tid; c < QXS2 / 8; c += 256) {
    union { unsigned short u[16]; ushort8x v[2]; } b;
    b.v[0] = *(const ushort8x*)(qg + ((8 * c) & (Lz - 1)));
    b.v[1] = *(const ushort8x*)(qg + ((8 * c + 8) & (Lz - 1)));
    #pragma unroll
    for (int s = 0; s < 8; ++s) {
      ushort8x w;
      #pragma unroll
      for (int t = 0; t < 8; ++t) w[t] = b.u[s + t];
      *(ushort8x*)(qx + s * QXS2 + 8 * c) = w;
    }
  }
  __syncthreads();

  const int lane = tid & 63;
  const int wv = tid >> 6;
  const int m = lane & 15;
  const int quad = lane >> 4;
  const int s = m & 7;
  const unsigned short* qxs = qx + s * QXS2 + (m & 8) + 8 * quad;
  const int bb0 = Lz + 8 * quad - 16 * m - 256 * wv;  // >= 1040

  floatx4 acc0 = {0.f, 0.f, 0.f, 0.f};
  floatx4 acc1 = {0.f, 0.f, 0.f, 0.f};
  #pragma unroll 4
  for (int t0 = 0; t0 < Lz; t0 += 32) {
    half8x a = *(const half8x*)(qxs + t0);
    const int x0 = (bb0 + t0) & (Lz - 1);
    const int x1 = (x0 + 1024) & (Lz - 1);
    half8x b0 = *(const half8x*)(ke + x0);
    half8x b1 = *(const half8x*)(ke + x1);
    acc0 = __builtin_amdgcn_mfma_f32_16x16x32_f16(a, b0, acc0, 0, 0, 0);
    acc1 = __builtin_amdgcn_mfma_f32_16x16x32_f16(a, b1, acc1, 0, 0, 0);
  }

  // --- per-wave top-15 from registers (no barriers) ---
  const int tbase = 256 * wv + 4 * quad + 16 * m;
  float vals[8];
  #pragma unroll
  for (int r = 0; r < 4; ++r) {
    vals[r] = acc0[r];
    vals[4 + r] = acc1[r];
  }
  for (int it = 0; it < KTOP; ++it) {
    float bv = vals[0];
    int bj = 0;
    #pragma unroll
    for (int j = 1; j < 8; ++j)
      if (vals[j] > bv) { bv = vals[j]; bj = j; }
    int bi = tbase + (bj & 3) + ((bj >> 2) << 10);
    #pragma unroll
    for (int off = 1; off < 64; off <<= 1) {
      const float ov = __shfl_xor(bv, off, 64);
      const int oi = __shfl_xor(bi, off, 64);
      if (ov > bv || (ov == bv && oi < bi)) { bv = ov; bi = oi; }
    }
    if (lane == it) { cv[wv * KTOP + it] = bv; ci[wv * KTOP + it] = bi; }
    const int rel = bi - tbase;
    #pragma unroll
    for (int j = 0; j < 8; ++j) {
      if (rel == ((j & 3) + ((j >> 2) << 10))) vals[j] = -3.0e38f;
    }
  }
  __syncthreads();

  // --- wave 0 merges 60 candidates -> top-15 + softmax ---
  if (wv == 0) {
    float v = (lane < 4 * KTOP) ? cv[lane] : -3.0e38f;
    int ix = (lane < 4 * KTOP) ? ci[lane] : 0x7fffffff;
    float gmax = 0.f, esum = 0.f, selv = 0.f;
    int seli = 0;
    for (int it = 0; it < KTOP; ++it) {
      float bv = v;
      int bi = ix;
      #pragma unroll
      for (int off = 1; off < 64; off <<= 1) {
        const float ov = __shfl_xor(bv, off, 64);
        const int oi = __shfl_xor(bi, off, 64);
        if (ov > bv || (ov == bv && oi < bi)) { bv = ov; bi = oi; }
      }
      if (it == 0) gmax = bv;
      esum += expf(bv - gmax);
      if (lane == it) { selv = bv; seli = bi; }
      if (ix == bi) v = -3.0e38f;
    }
    if (lane < KTOP) {
      const size_t ob = (size_t)blockIdx.x * KTOP;
      Wk[ob + lane] = expf(selv - gmax) / esum;
      Ik[ob + lane] = seli;
    }
  }
}

// ---------------------------------------------------------------------------
// Fused gather: out[b,l,d] = sum_k w[b,d,k] * v[b,(l+I[b,d,k]) mod L, d]
// Block = 8 d-channels; v staged fp16 in LDS [dl][l]; out written (L,D)
// through a padded LDS tile. grid (D/8, B), 256 threads.
// ---------------------------------------------------------------------------
__global__ __launch_bounds__(256) void gather_fused(
    const float* __restrict__ v, const float* __restrict__ Wk,
    const int* __restrict__ Ik, float* __restrict__ out) {
  __shared__ _Float16 ls[8 * Lz];   // 32 KB
  __shared__ float os[256 * 9];     // 9 KB padded out-staging
  const int tid = threadIdx.x;
  const int d0 = blockIdx.x * 8;
  const int b = blockIdx.y;
  const float* vb = v + (size_t)b * Lz * Dz;
  float* ob = out + (size_t)b * Lz * Dz;

  // stage v[:, d0..d0+8) -> ls[dl][l] fp16
  for (int it = 0; it < 16; ++it) {
    const int sslot = tid + 256 * it;  // 4096 slots
    const int l = sslot >> 1, c = sslot & 1;
    const float4 v4 = *(const float4*)&vb[(size_t)l * Dz + d0 + 4 * c];
    ls[(4 * c + 0) * Lz + l] = (_Float16)v4.x;
    ls[(4 * c + 1) * Lz + l] = (_Float16)v4.y;
    ls[(4 * c + 2) * Lz + l] = (_Float16)v4.z;
    ls[(4 * c + 3) * Lz + l] = (_Float16)v4.w;
  }

  const int dl = tid & 7;
  const int lg = tid >> 3;  // [0,32)
  const size_t wb = ((size_t)b * Dz + d0 + dl) * KTOP;
  float wreg[KTOP];
  int ireg[KTOP];
  #pragma unroll
  for (int k = 0; k < KTOP; ++k) {
    wreg[k] = Wk[wb + k];
    ireg[k] = Ik[wb + k];
  }
  __syncthreads();

  const _Float16* lp = ls + dl * Lz;
  for (int lt = 0; lt < 8; ++lt) {
    const int lbase = lt * 256 + lg * 8;
    float acc[8] = {0.f, 0.f, 0.f, 0.f, 0.f, 0.f, 0.f, 0.f};
    for (int k = 0; k < KTOP; ++k) {
      const float w = wreg[k];
      const int id = ireg[k];
      #pragma unroll
      for (int j = 0; j < 8; ++j)
        acc[j] += w * (float)lp[(lbase + j + id) & (Lz - 1)];
    }
    __syncthreads();  // previous tile's os reads complete
    #pragma unroll
    for (int j = 0; j < 8; ++j) os[(lg * 8 + j) * 9 + dl] = acc[j];
    __syncthreads();
    #pragma unroll
    for (int c2 = 0; c2 < 2; ++c2) {
      const int sl = tid + 256 * c2;  // 512 slots
      const int l = sl >> 1, c = sl & 1;
      float4 o;
      o.x = os[l * 9 + 4 * c + 0];
      o.y = os[l * 9 + 4 * c + 1];
      o.z = os[l * 9 + 4 * c + 2];
      o.w = os[l * 9 + 4 * c + 3];
      *(float4*)&ob[(size_t)(lt * 256 + l) * Dz + d0 + 4 * c] = o;
    }
  }
}

// ---------------------------------------------------------------------------
extern "C" void kernel_launch(void* const* d_in, const int* in_sizes, int n_in,
                              void* d_out, int out_size, void* d_ws, size_t ws_size,
                              hipStream_t stream) {
  const float* Q = (const float*)d_in[0];
  const float* K = (const float*)d_in[1];
  const float* V = (const float*)d_in[2];
  const float* WQw = (const float*)d_in[3];
  const float* WQb = (const float*)d_in[4];
  const float* WKw = (const float*)d_in[5];
  const float* WKb = (const float*)d_in[6];
  const float* WVw = (const float*)d_in[7];
  const float* WVb = (const float*)d_in[8];
  float* out = (float*)d_out;

  const size_t CH = (size_t)Bz * Dz;        // 4096
  const size_t NEL = (size_t)Bz * Lz * Dz;  // 8388608
  const int M = Bz * Lz;                    // 16384

  char* ws = (char*)d_ws;
  _Float16* qT = (_Float16*)ws;                      // NEL fp16 (B,D,L)
  _Float16* kT = qT + NEL;                           // NEL fp16
  float* vbuf = (float*)(ws + 2 * NEL * 2);          // NEL fp32 (B,L,D)
  char* p = (char*)(vbuf + NEL);
  _Float16* WQt = (_Float16*)p;                      // 512x512 fp16 each
  _Float16* WKt = WQt + (size_t)Dz * Dz;
  _Float16* WVt = WKt + (size_t)Dz * Dz;
  float* Wk = (float*)(WVt + (size_t)Dz * Dz);
  int* Ik = (int*)(Wk + CH * KTOP);

  dim3 gemm_grid(Dz / 128, M / 128);  // (4, 128)
  dim3 tr_block(32, 8);

  // weights -> fp16 transposed (N x K)
  wtrans3<<<dim3(16, 16, 3), tr_block, 0, stream>>>(WQw, WKw, WVw, WQt, WKt, WVt);

  // q, k -> fp16 transposed (B,D,L); v -> fp32 natural (B,L,D)
  gemm_fused<<<gemm_grid, dim3(256), 0, stream>>>(Q, WQt, WQb, (void*)qT, 1);
  gemm_fused<<<gemm_grid, dim3(256), 0, stream>>>(K, WKt, WKb, (void*)kT, 1);
  gemm_fused<<<gemm_grid, dim3(256), 0, stream>>>(V, WVt, WVb, (void*)vbuf, 0);

  // correlation (MFMA) + top-k + softmax per channel
  corr_mfma_topk<<<dim3((unsigned)CH), dim3(256), 0, stream>>>(qT, kT, Wk, Ik);

  // fused gather -> out (B,L,D)
  gather_fused<<<dim3(Dz / 8, Bz), dim3(256), 0, stream>>>(vbuf, Wk, Ik, out);
}